// Round 8
// baseline (18.506 us; speedup 1.0000x reference)
//
#include <hip/hip_runtime.h>

#define BB 8
#define SS 4096
#define DD 1024
#define TEMP 0.1f
#define PADV -100.0f
#define EPSV 1e-8f

typedef unsigned long long u64;

// Dispatch 1 (tiny): labels -> per-64-position bitmasks.
// vmask bit = (label != -100), lmask bit = (label == 1). 64 words per batch.
// 64 blocks x 256 thr, no LDS, no barriers, no scan.
__global__ __launch_bounds__(256) void mask_kernel(const int* __restrict__ labels,
                                                   u64* __restrict__ vmask,
                                                   u64* __restrict__ lmask) {
    int blk  = blockIdx.x;          // 0..63
    int b    = blk >> 3;
    int wg   = blk & 7;
    int lane = threadIdx.x & 63;
    int wv   = threadIdx.x >> 6;    // 0..3
#pragma unroll
    for (int k = 0; k < 2; ++k) {
        int w  = wg * 8 + wv * 2 + k;
        int xv = labels[b * SS + w * 64 + lane];   // coalesced
        u64 vb = __ballot(xv != -100);
        u64 lb = __ballot(xv == 1);
        if (lane == 0) {
            vmask[b * 64 + w] = vb;
            lmask[b * 64 + w] = lb;
        }
    }
}

// index of k-th (0-based) set bit of m; caller guarantees popcount(m) > k.
__device__ __forceinline__ int kth_set_bit(u64 m, int k) {
    int p = 0;
    unsigned int lo = (unsigned int)m;
    int c = __popc(lo);
    if (k >= c) { k -= c; p = 32; lo = (unsigned int)(m >> 32); }
    c = __popc(lo & 0xFFFFu);
    if (k >= c) { k -= c; p += 16; lo >>= 16; }
    c = __popc(lo & 0xFFu);
    if (k >= c) { k -= c; p += 8;  lo >>= 8; }
    c = __popc(lo & 0xFu);
    if (k >= c) { k -= c; p += 4;  lo >>= 4; }
    c = __popc(lo & 0x3u);
    if (k >= c) { k -= c; p += 2;  lo >>= 2; }
    c = __popc(lo & 0x1u);
    if (k >= c) { p += 1; }
    return p;
}

// Wave-collective: map rank r -> (original position, label value).
// Lane w holds mask word w and its exclusive prefix pref / count cw.
// r < 0 -> pos = -1. Exactly one lane matches valid r; broadcast via shfl.
__device__ __forceinline__ void resolve(int r, u64 vm, u64 lm, int pref, int cw,
                                        int lane, int& pos, int& val) {
    bool mine = (r >= pref) && (r < pref + cw);   // false on all lanes if r < 0
    u64 ball = __ballot(mine);
    pos = -1; val = 0;
    if (ball) {                                   // wave-uniform branch
        int src = __builtin_ctzll(ball);
        int bp  = kth_set_bit(vm, r - pref);      // bounded garbage off-lane
        int pc  = lane * 64 + bp;
        int vc  = (int)((lm >> bp) & 1ull);
        pos = __shfl(pc, src, 64);
        val = __shfl(vc, src, 64);
    }
}

// Dispatch 2: one wave per 2 consecutive ranks. Wave rebuilds the global
// prefix from the 512 B valid-mask (L1-hot), locates its 3 slot positions,
// then does the proven R6 pair math with direct global float4 loads.
// Writes BOTH outputs (cos + labels-as-float) including pads.
__global__ __launch_bounds__(256) void cos_kernel(const float* __restrict__ x,
                                                  const u64* __restrict__ vmask,
                                                  const u64* __restrict__ lmask,
                                                  float* __restrict__ out_cos,
                                                  float* __restrict__ out_lab) {
    int b    = blockIdx.y;
    int lane = threadIdx.x & 63;
    int wid  = threadIdx.x >> 6;
    int j0   = blockIdx.x * 8 + wid * 2;    // this wave's first rank

    u64 vm = vmask[b * 64 + lane];
    u64 lm = lmask[b * 64 + lane];
    int cw = __popcll(vm);
    int pref = cw;
#pragma unroll
    for (int off = 1; off < 64; off <<= 1) {
        int n = __shfl_up(pref, off, 64);
        if (lane >= off) pref += n;
    }
    int cnt = __shfl(pref, 63, 64);
    pref -= cw;                             // exclusive prefix

    float* cosp = out_cos + b * SS + j0;
    float* labp = out_lab + b * SS + j0;

    if (j0 >= cnt) {                        // wave-uniform: both ranks are pads
        if (lane == 0) {
            *(float2*)cosp = make_float2(PADV, PADV);
            *(float2*)labp = make_float2(PADV, PADV);
        }
        return;
    }

    bool p1 = (j0 + 1 < cnt);
    int r0 = j0;
    int r1 = p1 ? (j0 + 1) : 0;                              // wrap when last
    int r2 = p1 ? ((j0 + 2 == cnt) ? 0 : j0 + 2) : -1;

    int P0, V0, P1, V1, P2, V2;
    resolve(r0, vm, lm, pref, cw, lane, P0, V0);
    resolve(r1, vm, lm, pref, cw, lane, P1, V1);
    resolve(r2, vm, lm, pref, cw, lane, P2, V2);
    int P2s = (P2 < 0) ? P1 : P2;           // keep pointer valid when !p1

    const float* xb = x + (size_t)b * SS * DD + (size_t)lane * 4;
    const float* pa = xb + (size_t)P0  * DD;
    const float* pb = xb + (size_t)P1  * DD;
    const float* pc = xb + (size_t)P2s * DD;

    float4 A[4], B[4], C[4];
#pragma unroll
    for (int q = 0; q < 4; ++q) {
        A[q] = *(const float4*)(pa + q * 256);
        B[q] = *(const float4*)(pb + q * 256);
        C[q] = *(const float4*)(pc + q * 256);
    }

    float na = 0.f, nb = 0.f, nc = 0.f, dab = 0.f, dbc = 0.f;
#pragma unroll
    for (int q = 0; q < 4; ++q) {
        na  += A[q].x*A[q].x + A[q].y*A[q].y + A[q].z*A[q].z + A[q].w*A[q].w;
        nb  += B[q].x*B[q].x + B[q].y*B[q].y + B[q].z*B[q].z + B[q].w*B[q].w;
        nc  += C[q].x*C[q].x + C[q].y*C[q].y + C[q].z*C[q].z + C[q].w*C[q].w;
        dab += A[q].x*B[q].x + A[q].y*B[q].y + A[q].z*B[q].z + A[q].w*B[q].w;
        dbc += B[q].x*C[q].x + B[q].y*C[q].y + B[q].z*C[q].z + B[q].w*C[q].w;
    }
#pragma unroll
    for (int off = 32; off; off >>= 1) {
        na  += __shfl_xor(na,  off, 64);
        nb  += __shfl_xor(nb,  off, 64);
        nc  += __shfl_xor(nc,  off, 64);
        dab += __shfl_xor(dab, off, 64);
        dbc += __shfl_xor(dbc, off, 64);
    }

    if (lane == 0) {
        float c0 = dab / fmaxf(sqrtf(na) * sqrtf(nb), EPSV) / TEMP;
        float c1 = p1 ? (dbc / fmaxf(sqrtf(nb) * sqrtf(nc), EPSV) / TEMP) : PADV;
        *(float2*)cosp = make_float2(c0, c1);
        *(float2*)labp = make_float2((float)V0, p1 ? (float)V1 : PADV);
    }
}

extern "C" void kernel_launch(void* const* d_in, const int* in_sizes, int n_in,
                              void* d_out, int out_size, void* d_ws, size_t ws_size,
                              hipStream_t stream) {
    const float* seq    = (const float*)d_in[0];   // [B,S,D] f32
    const int*   labels = (const int*)d_in[1];     // [B,S] i32

    float* out_cos = (float*)d_out;                // [B,S]
    float* out_lab = (float*)d_out + BB * SS;      // [B,S] as floats

    u64* vmask = (u64*)d_ws;                       // B*64 words
    u64* lmask = vmask + BB * 64;                  // B*64 words

    mask_kernel<<<64, 256, 0, stream>>>(labels, vmask, lmask);

    dim3 grid(SS / 8, BB);                         // 4 waves/block, 2 ranks/wave
    cos_kernel<<<grid, 256, 0, stream>>>(seq, vmask, lmask, out_cos, out_lab);
}

// Round 9
// 16.669 us; speedup vs baseline: 1.1102x; 1.1102x over previous
//
#include <hip/hip_runtime.h>

#define BB 8
#define SS 4096
#define DD 1024
#define TEMP 0.1f
#define PADV -100.0f
#define EPSV 1e-8f

// One block (1024 threads) per batch. Scan labels for compacted ranks, then
// SCATTER-build the pair-descriptor table directly (no LDS pos[] round trip,
// one barrier total): position p with rank r writes desc[r].x = p and
// desc[(r-1+c)%c].y = p (disjoint 4B addresses -> no race). Pads (-1,-1) and
// both output chunks' -100 pads are written by their rank-owning threads.
__global__ __launch_bounds__(1024) void compact_kernel(const int* __restrict__ labels,
                                                       int2* __restrict__ desc,
                                                       float* __restrict__ out_cos,
                                                       float* __restrict__ out_lab) {
    int b = blockIdx.x;
    int t = threadIdx.x;
    int lane = t & 63, wave = t >> 6;

    __shared__ int wsum[16];

    int4 v = ((const int4*)(labels + b * SS))[t];
    int vals[4] = {v.x, v.y, v.z, v.w};
    int mycnt = (vals[0] != -100) + (vals[1] != -100) + (vals[2] != -100) + (vals[3] != -100);

    int scan = mycnt;
#pragma unroll
    for (int off = 1; off < 64; off <<= 1) {
        int n = __shfl_up(scan, off, 64);
        if (lane >= off) scan += n;
    }
    if (lane == 63) wsum[wave] = scan;
    __syncthreads();

    int wbase = 0, c = 0;
#pragma unroll
    for (int w = 0; w < 16; ++w) {
        int s = wsum[w];
        wbase += (w < wave) ? s : 0;
        c += s;
    }
    int r = wbase + scan - mycnt;          // this thread's first rank

    int2*  db = desc + (size_t)b * SS;
    float* lb = out_lab + b * SS;

    // valid positions: label out + desc scatter
#pragma unroll
    for (int i = 0; i < 4; ++i) {
        if (vals[i] != -100) {
            int p = 4 * t + i;
            lb[r] = (float)vals[i];
            db[r].x = p;
            int rp = (r == 0) ? (c - 1) : (r - 1);
            db[rp].y = p;
            ++r;
        }
    }
    // pads for ranks >= c: both chunks + desc sentinel
#pragma unroll
    for (int i = 0; i < 4; ++i) {
        int s = 4 * t + i;
        if (s >= c) {
            lb[s] = PADV;
            out_cos[b * SS + s] = PADV;
            db[s] = make_int2(-1, -1);
        }
    }
}

// One WAVE per 2 consecutive ranks (R6-proven best variant, unchanged).
// Single int4 descriptor load (j0 even -> 16B aligned, both pairs:
// (i0,i1,i1,i2)), then 3 parallel vector loads; 5-value butterfly reduce.
__global__ __launch_bounds__(256) void cos_kernel(const float* __restrict__ x,
                                                  const int2* __restrict__ desc,
                                                  float* __restrict__ out_cos) {
    int b    = blockIdx.y;
    int lane = threadIdx.x & 63;
    int wid  = threadIdx.x >> 6;
    int j0   = (blockIdx.x * 4 + wid) * 2;

    int4 D = *(const int4*)(desc + (size_t)b * SS + j0);
    if (D.x < 0) return;                     // pads already written by compact
    bool p1 = (D.z >= 0);
    int i0 = D.x, i1 = D.y;
    int i2 = p1 ? D.w : D.y;                 // keep pointer valid when !p1

    const float* xb = x + (size_t)b * SS * DD + (size_t)lane * 4;
    const float* pa = xb + (size_t)i0 * DD;
    const float* pb = xb + (size_t)i1 * DD;
    const float* pc = xb + (size_t)i2 * DD;

    float4 A[4], B[4], C[4];
#pragma unroll
    for (int q = 0; q < 4; ++q) {
        A[q] = *(const float4*)(pa + q * 256);
        B[q] = *(const float4*)(pb + q * 256);
        C[q] = *(const float4*)(pc + q * 256);
    }

    float na = 0.f, nb = 0.f, nc = 0.f, dab = 0.f, dbc = 0.f;
#pragma unroll
    for (int q = 0; q < 4; ++q) {
        na  += A[q].x*A[q].x + A[q].y*A[q].y + A[q].z*A[q].z + A[q].w*A[q].w;
        nb  += B[q].x*B[q].x + B[q].y*B[q].y + B[q].z*B[q].z + B[q].w*B[q].w;
        nc  += C[q].x*C[q].x + C[q].y*C[q].y + C[q].z*C[q].z + C[q].w*C[q].w;
        dab += A[q].x*B[q].x + A[q].y*B[q].y + A[q].z*B[q].z + A[q].w*B[q].w;
        dbc += B[q].x*C[q].x + B[q].y*C[q].y + B[q].z*C[q].z + B[q].w*C[q].w;
    }
#pragma unroll
    for (int off = 32; off; off >>= 1) {
        na  += __shfl_xor(na,  off, 64);
        nb  += __shfl_xor(nb,  off, 64);
        nc  += __shfl_xor(nc,  off, 64);
        dab += __shfl_xor(dab, off, 64);
        dbc += __shfl_xor(dbc, off, 64);
    }

    if (lane == 0) {
        float r0 = dab / fmaxf(sqrtf(na) * sqrtf(nb), EPSV) / TEMP;
        float* op = out_cos + b * SS + j0;
        if (p1) {
            float r1 = dbc / fmaxf(sqrtf(nb) * sqrtf(nc), EPSV) / TEMP;
            *(float2*)op = make_float2(r0, r1);
        } else {
            *op = r0;
        }
    }
}

extern "C" void kernel_launch(void* const* d_in, const int* in_sizes, int n_in,
                              void* d_out, int out_size, void* d_ws, size_t ws_size,
                              hipStream_t stream) {
    const float* seq    = (const float*)d_in[0];   // [B,S,D] f32
    const int*   labels = (const int*)d_in[1];     // [B,S] i32

    float* out_cos = (float*)d_out;                // [B,S]
    float* out_lab = (float*)d_out + BB * SS;      // [B,S] as floats

    int2* desc = (int2*)d_ws;                      // B*S int2 descriptors

    compact_kernel<<<BB, 1024, 0, stream>>>(labels, desc, out_cos, out_lab);

    dim3 grid(SS / 8, BB);                         // 4 waves/block, 2 ranks/wave
    cos_kernel<<<grid, 256, 0, stream>>>(seq, desc, out_cos);
}